// Round 14
// baseline (129.377 us; speedup 1.0000x reference)
//
#include <hip/hip_runtime.h>
#include <math.h>

#define BNS 0.99999500003749981f  // 1/sqrt(1+1e-5)

typedef short          bf16x8  __attribute__((ext_vector_type(8)));
typedef float          f32x4   __attribute__((ext_vector_type(4)));
typedef unsigned short u16x8   __attribute__((ext_vector_type(8)));
typedef unsigned short u16x4   __attribute__((ext_vector_type(4)));
typedef unsigned short ushort_t;

__device__ inline ushort_t f2b(float f) {
    union { float f; unsigned int u; } x; x.f = f;
    unsigned int u = x.u;
    unsigned int r = (u + 0x7FFFu + ((u >> 16) & 1u)) >> 16;   // RNE
    return (ushort_t)r;
}
__device__ inline float b2f(ushort_t s) {
    union { unsigned int u; float f; } x; x.u = ((unsigned int)s) << 16;
    return x.f;
}

// async global->LDS, 16B per lane; LDS dest is wave-uniform base (+lane*16 by HW)
__device__ inline void glds16(const ushort_t* gp, void* lp) {
    __builtin_amdgcn_global_load_lds(
        (const __attribute__((address_space(1))) unsigned int*)gp,
        (__attribute__((address_space(3))) unsigned int*)lp, 16, 0, 0);
}

// counted waitcnt (T4): wait until <=N vmem outstanding; optional lgkm drain
template<int N, bool LG0>
__device__ __forceinline__ void wait_v() {
    if constexpr (LG0) {
        if constexpr (N == 0)  asm volatile("s_waitcnt vmcnt(0) lgkmcnt(0)" ::: "memory");
        if constexpr (N == 2)  asm volatile("s_waitcnt vmcnt(2) lgkmcnt(0)" ::: "memory");
        if constexpr (N == 3)  asm volatile("s_waitcnt vmcnt(3) lgkmcnt(0)" ::: "memory");
        if constexpr (N == 4)  asm volatile("s_waitcnt vmcnt(4) lgkmcnt(0)" ::: "memory");
        if constexpr (N == 5)  asm volatile("s_waitcnt vmcnt(5) lgkmcnt(0)" ::: "memory");
        if constexpr (N == 6)  asm volatile("s_waitcnt vmcnt(6) lgkmcnt(0)" ::: "memory");
        if constexpr (N == 8)  asm volatile("s_waitcnt vmcnt(8) lgkmcnt(0)" ::: "memory");
        if constexpr (N == 9)  asm volatile("s_waitcnt vmcnt(9) lgkmcnt(0)" ::: "memory");
        if constexpr (N == 10) asm volatile("s_waitcnt vmcnt(10) lgkmcnt(0)" ::: "memory");
        if constexpr (N == 12) asm volatile("s_waitcnt vmcnt(12) lgkmcnt(0)" ::: "memory");
        if constexpr (N == 16) asm volatile("s_waitcnt vmcnt(16) lgkmcnt(0)" ::: "memory");
    } else {
        if constexpr (N == 0)  asm volatile("s_waitcnt vmcnt(0)" ::: "memory");
        if constexpr (N == 2)  asm volatile("s_waitcnt vmcnt(2)" ::: "memory");
        if constexpr (N == 3)  asm volatile("s_waitcnt vmcnt(3)" ::: "memory");
        if constexpr (N == 4)  asm volatile("s_waitcnt vmcnt(4)" ::: "memory");
        if constexpr (N == 5)  asm volatile("s_waitcnt vmcnt(5)" ::: "memory");
        if constexpr (N == 6)  asm volatile("s_waitcnt vmcnt(6)" ::: "memory");
        if constexpr (N == 8)  asm volatile("s_waitcnt vmcnt(8)" ::: "memory");
        if constexpr (N == 9)  asm volatile("s_waitcnt vmcnt(9)" ::: "memory");
        if constexpr (N == 10) asm volatile("s_waitcnt vmcnt(10)" ::: "memory");
        if constexpr (N == 12) asm volatile("s_waitcnt vmcnt(12)" ::: "memory");
        if constexpr (N == 16) asm volatile("s_waitcnt vmcnt(16)" ::: "memory");
    }
}
// runtime->template dispatch; folds to one call per unrolled iteration
#define WAITSW(nn, LG) do { switch (nn) {                       \
    case 0:  wait_v<0,  LG>(); break;                           \
    case 2:  wait_v<2,  LG>(); break;                           \
    case 3:  wait_v<3,  LG>(); break;                           \
    case 4:  wait_v<4,  LG>(); break;                           \
    case 5:  wait_v<5,  LG>(); break;                           \
    case 6:  wait_v<6,  LG>(); break;                           \
    case 8:  wait_v<8,  LG>(); break;                           \
    case 9:  wait_v<9,  LG>(); break;                           \
    case 10: wait_v<10, LG>(); break;                           \
    case 12: wait_v<12, LG>(); break;                           \
    default: wait_v<16, LG>(); break; } } while (0)

// ---------------- workspace element offsets (ushort units) ----------------
#define E_BWR   0u
#define E_BW1   147456u
#define E_BW2   163840u
#define E_BWE   172032u
#define E_BWO1  208896u
#define E_BWO2  430080u
#define E_ZP    446464u      // 64KB zero page (32768 el)
#define OFF_R1  524288u      // 8MB region   (byte 1048576)
#define OFF_R4  4718592u     // 8MB          (byte 9437184)
#define OFF_R2  8912896u     // 2MB          (byte 17825792)
#define OFF_R3  9961472u     // 2MB          (byte 19922944)
#define OFF_R6  11010048u    // 4MB          (byte 22020096)
#define OFF_R5  13107200u    // 16MB         (byte 26214400) end byte 42991616

// T16 activation layout: element (px, ci) of a CI-channel tensor lives at
//   (px>>4)*(CI*16) + (ci>>3)*128 + (px&15)*8 + (ci&7)

// ============================================================================
// prep_all: weight repack (OIHW f32 -> [kt][ci_oct][co][8] bf16) + zero page
//           + both NCHW->T16 activation conversions, one dispatch.
// ============================================================================
__device__ inline void wseg3(int idx, const float* src, ushort_t* dst,
                             int TAPS, int COT, int CIT, int CO_real) {
    int kt  = idx / (COT * 32);
    int r   = idx - kt * (COT * 32);
    int q   = r / (COT * 8);
    int r2  = r - q * (COT * 8);
    int co  = r2 >> 3;
    int e   = r2 & 7;
    int KCT = CIT >> 5;
    int tap = kt / KCT, j = kt - tap * KCT;
    int ci  = j * 32 + q * 8 + e;
    float v = (co < CO_real) ? src[((size_t)co * CIT + ci) * TAPS + tap] : 0.f;
    dst[idx] = f2b(v);
}

__device__ inline void cvt_t16(const float* __restrict__ in,
                               ushort_t* __restrict__ out,
                               int C, int LHW, int px, int npx) {
    if (px >= npx) return;
    int HW = 1 << LHW;
    int b = px >> LHW, phw = px & (HW - 1);
    const float* src = in + (size_t)b * C * HW + phw;
    unsigned base = (unsigned)(px >> 4) * (C * 16) + (unsigned)(px & 15) * 8;
    for (int c0 = 0; c0 < C; c0 += 8) {
        u16x8 o;
#pragma unroll
        for (int j = 0; j < 8; j++) o[j] = f2b(src[(size_t)(c0 + j) * HW]);
        *reinterpret_cast<u16x8*>(out + base + (c0 >> 3) * 128) = o;
    }
}

__global__ __launch_bounds__(256)
void prep_all(const float* wr, const float* w1, const float* w2,
              const float* we, const float* wo1, const float* wo2,
              const float* xh, const float* xl, ushort_t* ws0)
{
    int bx = blockIdx.x;
    int tid = threadIdx.x;
    if (bx < 1872) {
        int idx = bx * 256 + tid;
        const int n0 = 9*64*256;    // reduce   147456
        const int n1 = 64*256;      // w1        16384
        const int n2 = 64*128;      // w2         8192
        const int n3 = 9*32*128;    // enc       36864
        const int n4 = 9*128*192;   // out1     221184
        const int n5 = 128*128;     // out2      16384
        if (idx < n0) { wseg3(idx, wr,  ws0 + E_BWR,  9, 64, 256, 64);  return; } idx -= n0;
        if (idx < n1) { wseg3(idx, w1,  ws0 + E_BW1,  1, 64, 256, 64);  return; } idx -= n1;
        if (idx < n2) { wseg3(idx, w2,  ws0 + E_BW2,  1, 64, 128, 64);  return; } idx -= n2;
        if (idx < n3) { wseg3(idx, we,  ws0 + E_BWE,  9, 32, 128, 25);  return; } idx -= n3;
        if (idx < n4) { wseg3(idx, wo1, ws0 + E_BWO1, 9, 128, 192, 128); return; } idx -= n4;
        if (idx < n5) { wseg3(idx, wo2, ws0 + E_BWO2, 1, 128, 128, 128); return; } idx -= n5;
        if (idx < 32768) ws0[E_ZP + idx] = 0;   // zero page
        return;
    }
    bx -= 1872;
    if (bx < 64) { cvt_t16(xh, ws0 + OFF_R1, 256, 12, bx * 256 + tid, 16384); return; }
    bx -= 64;
    cvt_t16(xl, ws0 + OFF_R5, 128, 14, bx * 256 + tid, 65536);
}

// ============================================================================
// DUAL conv v2: xr = 3x3(xh_c, w_reduce) AND c1 = 1x1(xh_c, w1), CO split
// across gridDim.y (BN=32) -> 512 blocks = 2 blocks/CU (latency overlap).
// Uniform SS=3 loads/wave/phase. Depth-3 counted-vmcnt pipeline.
// ============================================================================
__global__ __launch_bounds__(256)
void conv_dual(const ushort_t* __restrict__ ws0,
               unsigned offA, unsigned offWr, unsigned offW1,
               const float* __restrict__ gR, const float* __restrict__ bR,
               const float* __restrict__ g1, const float* __restrict__ b1,
               ushort_t* __restrict__ outR, ushort_t* __restrict__ outC)
{
    constexpr int DEP = 3, NPH = 24, KCT = 8;
    constexpr int MF = 2;                       // px frags per wave (NF = 1)
    constexpr int WOFF = 4096;                  // act row (64px x 32ci)
    constexpr int ZS   = WOFF + 4 * 2048;       // 4 wt tiles (32co x 32ci)
    constexpr int BUF  = ZS + 16;
    __shared__ __align__(16) char lds[DEP * BUF];

    const unsigned ox = blockIdx.x;             // gridDim.x == 256
    const unsigned bx = (ox & 7) * 32 + (ox >> 3);   // XCD-chunked
    const int co_blk = blockIdx.y * 32;

    const int tid = threadIdx.x, w = tid >> 6, lane = tid & 63;
    const int l15 = lane & 15, lhi = lane >> 4;
    const int wpx = (w & 1) * 32, cw0 = (w >> 1) * 16;
    const int yb = (int)(bx & 63u);             // block = image row yb
    const unsigned pxc0 = bx * 4;               // 1KB act chunks

    if (tid < 4 * DEP) *(unsigned*)(lds + (tid >> 2) * BUF + ZS + (tid & 3) * 4) = 0u;

    int aA[3][MF];
#pragma unroll
    for (int dxi = 0; dxi < 3; ++dxi)
#pragma unroll
        for (int mf = 0; mf < MF; ++mf) {
            int pr = wpx + mf * 16 + l15 + dxi - 1;
            bool ok = (pr >= 0) && (pr < 64);
            aA[dxi][mf] = ok ? (((pr >> 4) << 10) + (lhi << 8) + ((pr & 15) << 4)) : ZS;
        }
    const int wA = (lhi * 32 + cw0 + l15) * 16;  // within a 2048B wt tile

    f32x4 acc[MF], acc2[MF];
#pragma unroll
    for (int mf = 0; mf < MF; ++mf) {
        acc[mf]  = (f32x4){0.f, 0.f, 0.f, 0.f};
        acc2[mf] = (f32x4){0.f, 0.f, 0.f, 0.f};
    }

    auto stage = [&](int p, int bsel) {
        char* lb = lds + bsel * BUF;
        const int dyi = p >> 3, kc = p & 7;
        const int dy = dyi - 1;
        const bool rowv = (yb + dy >= 0) && (yb + dy < 64);
        // act: 1 load/wave (4 x 1KB chunks)
        unsigned s = rowv
            ? offA + (unsigned)((int)pxc0 + dy * 4 + w) * 4096u
                   + (unsigned)(kc * 512) + (unsigned)(lane * 8)
            : E_ZP + (unsigned)(lane * 8);
        glds16(ws0 + s, lb + w * 1024);
        // weights: 2 loads/wave. dy=0: 8 units (3 dx + w1); else 6 units (dup).
        const int nunits = (dyi == 1) ? 8 : 6;
#pragma unroll
        for (int i = 0; i < 2; ++i) {
            int t3 = (i * 4 + w) % nunits;
            int tl = t3 >> 1, uu = t3 & 1;
            int el  = uu * 512 + lane * 8;
            int q   = el >> 8;
            int col = (el & 255) >> 3;
            unsigned src = (tl < 3)
                ? offWr + (unsigned)(((dyi * 3 + tl) * KCT + kc) * 2048)
                        + (unsigned)(q * 512) + (unsigned)((co_blk + col) * 8)
                : offW1 + (unsigned)(kc * 2048)
                        + (unsigned)(q * 512) + (unsigned)((co_blk + col) * 8);
            glds16(ws0 + src, lb + WOFF + tl * 2048 + uu * 1024);
        }
    };

    auto step = [&](int p, int bsel) {
        const char* lb = lds + bsel * BUF;
        const int dyi = p >> 3;
        __builtin_amdgcn_s_setprio(1);
#pragma unroll
        for (int t = 0; t < 3; ++t) {
            bf16x8 af[MF];
#pragma unroll
            for (int mf = 0; mf < MF; ++mf)
                af[mf] = *reinterpret_cast<const bf16x8*>(lb + aA[t][mf]);
            bf16x8 wf = *reinterpret_cast<const bf16x8*>(lb + WOFF + t * 2048 + wA);
#pragma unroll
            for (int mf = 0; mf < MF; ++mf)
                acc[mf] = __builtin_amdgcn_mfma_f32_16x16x32_bf16(
                    wf, af[mf], acc[mf], 0, 0, 0);
        }
        if (dyi == 1) {
            bf16x8 af[MF];
#pragma unroll
            for (int mf = 0; mf < MF; ++mf)
                af[mf] = *reinterpret_cast<const bf16x8*>(lb + aA[1][mf]);
            bf16x8 wf = *reinterpret_cast<const bf16x8*>(lb + WOFF + 3 * 2048 + wA);
#pragma unroll
            for (int mf = 0; mf < MF; ++mf)
                acc2[mf] = __builtin_amdgcn_mfma_f32_16x16x32_bf16(
                    wf, af[mf], acc2[mf], 0, 0, 0);
        }
        __builtin_amdgcn_s_setprio(0);
    };

    stage(0, 0); stage(1, 1);
#pragma unroll
    for (int p = 0; p < NPH; ++p) {
        if (p + 2 < NPH) stage(p + 2, (p + 2) % 3);
        int rem = NPH - 1 - p;
        int nn = (rem >= 2 ? 2 : rem) * 3;
        if (p == 0) WAITSW(nn, true); else WAITSW(nn, false);
        __builtin_amdgcn_s_barrier();
        __builtin_amdgcn_sched_barrier(0);
        step(p, p % 3);
        __builtin_amdgcn_sched_barrier(0);
        if (p + 1 < NPH) __builtin_amdgcn_s_barrier();
    }

    // epilogue: two T16 bf16 outputs, COT = 64
#pragma unroll
    for (int which = 0; which < 2; ++which) {
        const float* gg = which ? g1 : gR;
        const float* bb = which ? b1 : bR;
        ushort_t* oo = which ? outC : outR;
        const int cg = co_blk + cw0 + (lhi << 2);
        float sc[4], bi[4];
#pragma unroll
        for (int r = 0; r < 4; r++) { sc[r] = gg[cg + r] * BNS; bi[r] = bb[cg + r]; }
#pragma unroll
        for (int mf = 0; mf < MF; ++mf) {
            f32x4 a = which ? acc2[mf] : acc[mf];
            u16x4 ov;
#pragma unroll
            for (int r = 0; r < 4; r++)
                ov[r] = f2b(fmaxf(fmaf(a[r], sc[r], bi[r]), 0.f));
            int px = (int)bx * 64 + wpx + mf * 16 + l15;
            unsigned off = (unsigned)(px >> 4) * 1024
                         + (unsigned)(cg >> 3) * 128
                         + (unsigned)(px & 15) * 8 + (unsigned)(cg & 7);
            *reinterpret_cast<u16x4*>(oo + off) = ov;
        }
    }
}

// ============================================================================
// LDS-staged implicit-GEMM conv, counted-vmcnt DEP-buffer pipeline (T4),
// dy-major phases, s_setprio around MFMA (T5), WSX-way px wave split.
// EPI: 0 = T16 bf16, 1 = NCHW f32 direct, 2 = T16 + fused softmax-25,
//      4 = FUSED second 1x1 GEMM (w2 at offW2, 128ch) + bn2 + relu
//          + f32 NCHW out via LDS-exchange coalesced stores.
// ============================================================================
template<int TAPS, int BM, int CIA, int CIB, int COT, int BN, int G,
         int WSX, int DEP, int EPI>
__global__ __launch_bounds__(256)
void conv_lds(const ushort_t* __restrict__ ws0,
              unsigned offA, unsigned offB, unsigned offW,
              const float* __restrict__ g, const float* __restrict__ bia,
              int COclamp, void* __restrict__ outp,
              int H, int LHW, int relu,
              unsigned offW2, const float* __restrict__ g2,
              const float* __restrict__ bia2)
{
    constexpr int KCA = CIA / 32, KCB = CIB / 32;
    constexpr int KCT = KCA + KCB;
    constexpr int NW  = (TAPS == 9) ? 3 : G;       // weight tiles per phase
    constexpr int ACP = (TAPS == 9) ? 1 : G;       // act 32ci-chunks per phase
    constexpr int NPH = (TAPS == 9) ? 3 * KCT : KCT / G;
    constexpr int WSY = 4 / WSX;
    constexpr int MF = BM / WSX / 16;              // px frags per wave
    constexpr int NF = BN / WSY / 16;              // co frags per wave
    constexpr int ACHUNK = BM / 16;                // 1KB units per act chunk
    constexpr int A4 = (ACP * ACHUNK + 3) / 4;     // act loads per wave/phase
    constexpr int WUNIT = BN / 16;                 // 1KB units per wt tile
    constexpr int TWU = NW * WUNIT;
    constexpr int W4 = (TWU + 3) / 4;              // wt loads per wave/phase
    constexpr int SS = A4 + W4;                    // uniform loads/wave/phase
    constexpr int WOFF = ACP * BM * 64;            // bytes: act region size
    constexpr int ZS   = WOFF + NW * BN * 64;      // per-buffer zero slot
    constexpr int BUF  = ZS + 16;
    constexpr int LBN3 = (BN == 128) ? 10 : (BN == 64) ? 9 : 8;  // log2(BN*8)
    __shared__ __align__(16) char lds[DEP * BUF];

    // XCD-chunked swizzle: real XCD = blockIdx.x % 8 (gridDim.x % 8 == 0).
    const unsigned nx = gridDim.x, ox = blockIdx.x;
    const unsigned qq = nx >> 3, xcd = ox & 7, k0 = ox >> 3;
    const unsigned bx = xcd * qq + k0;
    const int co_blk = blockIdx.y * BN;

    const int tid = threadIdx.x, w = tid >> 6, lane = tid & 63;
    const int l15 = lane & 15, lhi = lane >> 4;
    const int wpx = (w % WSX) * (BM / WSX);
    const int cw0 = (w / WSX) * (BN / WSY);
    const int yb = (int)(bx & (unsigned)(H - 1));      // BM == W: block = row yb
    const unsigned pxc0 = bx * ACHUNK;

    if (tid < 4 * DEP) *(unsigned*)(lds + (tid >> 2) * BUF + ZS + (tid & 3) * 4) = 0u;

    int aA[3][MF];
#pragma unroll
    for (int dxi = 0; dxi < 3; ++dxi) {
        const int dx = dxi - 1;
#pragma unroll
        for (int mf = 0; mf < MF; ++mf) {
            int pr = wpx + mf * 16 + l15 + dx;
            bool ok = (TAPS == 1) ? true : (pr >= 0 && pr < BM);
            aA[dxi][mf] = ok ? (((pr >> 4) << 10) + (lhi << 8) + ((pr & 15) << 4)) : ZS;
        }
    }
    int wA[NF];
#pragma unroll
    for (int nf = 0; nf < NF; ++nf)
        wA[nf] = (lhi * BN + cw0 + nf * 16 + l15) * 16;  // within a wt tile

    f32x4 acc[NF][MF];
#pragma unroll
    for (int nf = 0; nf < NF; ++nf)
#pragma unroll
        for (int mf = 0; mf < MF; ++mf)
            acc[nf][mf] = (f32x4){0.f, 0.f, 0.f, 0.f};

    auto stage = [&](int p, int bsel) {
        char* lb = lds + bsel * BUF;
        if constexpr (TAPS == 9) {
            const int dyi = p / KCT, kc = p - dyi * KCT;
            const int dy = dyi - 1;
            const bool isA = (kc < KCA);
            const int kcs = isA ? kc : kc - KCA;
            const int CI  = isA ? CIA : CIB;
            const unsigned offS = isA ? offA : offB;
            const bool rowv = (yb + dy >= 0) && (yb + dy < H);
#pragma unroll
            for (int i = 0; i < A4; ++i) {
                int u = (i * 4 + w) % ACHUNK;
                unsigned s = rowv
                    ? offS + (unsigned)((int)pxc0 + dy * ACHUNK + u) * (unsigned)(CI * 16)
                           + (unsigned)(kcs * 512) + (unsigned)(lane * 8)
                    : E_ZP + (unsigned)(lane * 8);
                glds16(ws0 + s, lb + u * 1024);
            }
#pragma unroll
            for (int i = 0; i < W4; ++i) {
                int t3 = (i * 4 + w) % TWU;
                int tl = t3 / WUNIT, uu = t3 - tl * WUNIT;
                unsigned wsrc = offW + (unsigned)((dyi * 3 + tl) * KCT + kc)
                                       * (unsigned)(COT * 32);
                int el  = uu * 512 + lane * 8;
                int q   = el >> LBN3;
                int col = (el & ((1 << LBN3) - 1)) >> 3;
                glds16(ws0 + wsrc + q * (COT * 8) + (co_blk + col) * 8,
                       lb + WOFF + tl * (BN * 64) + uu * 1024);
            }
        } else {
#pragma unroll
            for (int i = 0; i < A4; ++i) {
                int lin = (i * 4 + w) % (ACP * ACHUNK);
                int gc = lin / ACHUNK, u = lin - gc * ACHUNK;
                unsigned s = offA + (unsigned)(pxc0 + u) * (unsigned)(CIA * 16)
                           + (unsigned)((p * G + gc) * 512) + (unsigned)(lane * 8);
                glds16(ws0 + s, lb + gc * (BM * 64) + u * 1024);
            }
#pragma unroll
            for (int i = 0; i < W4; ++i) {
                int t3 = (i * 4 + w) % TWU;
                int tl = t3 / WUNIT, uu = t3 - tl * WUNIT;
                unsigned wsrc = offW + (unsigned)(p * G + tl) * (unsigned)(COT * 32);
                int el  = uu * 512 + lane * 8;
                int q   = el >> LBN3;
                int col = (el & ((1 << LBN3) - 1)) >> 3;
                glds16(ws0 + wsrc + q * (COT * 8) + (co_blk + col) * 8,
                       lb + WOFF + tl * (BN * 64) + uu * 1024);
            }
        }
    };

    auto step = [&](int p, int bsel) {
        const char* lb = lds + bsel * BUF;
        __builtin_amdgcn_s_setprio(1);                  // T5: favor MFMA waves
#pragma unroll
        for (int t = 0; t < NW; ++t) {
            const int dxi = (TAPS == 9) ? t : 1;
            const char* ab = lb + ((TAPS == 9) ? 0 : t * (BM * 64));
            bf16x8 af[MF], wf[NF];
#pragma unroll
            for (int mf = 0; mf < MF; ++mf)
                af[mf] = *reinterpret_cast<const bf16x8*>(ab + aA[dxi][mf]);
#pragma unroll
            for (int nf = 0; nf < NF; ++nf)
                wf[nf] = *reinterpret_cast<const bf16x8*>(
                    lb + WOFF + t * (BN * 64) + wA[nf]);
#pragma unroll
            for (int nf = 0; nf < NF; ++nf)
#pragma unroll
                for (int mf = 0; mf < MF; ++mf)
                    acc[nf][mf] = __builtin_amdgcn_mfma_f32_16x16x32_bf16(
                        wf[nf], af[mf], acc[nf][mf], 0, 0, 0);
        }
        __builtin_amdgcn_s_setprio(0);
    };

    stage(0, 0);
    if constexpr (DEP == 3) { if (1 < NPH) stage(1, 1); }
#pragma unroll
    for (int p = 0; p < NPH; ++p) {
        if (p + DEP - 1 < NPH) stage(p + DEP - 1, (p + DEP - 1) % DEP);
        int rem = NPH - 1 - p;
        int nn = (rem >= DEP - 1 ? DEP - 1 : rem) * SS;
        if (p == 0) WAITSW(nn, true); else WAITSW(nn, false);
        __builtin_amdgcn_s_barrier();
        __builtin_amdgcn_sched_barrier(0);
        step(p, p % DEP);
        __builtin_amdgcn_sched_barrier(0);
        if (p + 1 < NPH) __builtin_amdgcn_s_barrier();
    }

    // ---------------- epilogue ----------------
    if constexpr (EPI == 0) {
        ushort_t* o1 = (ushort_t*)outp;
#pragma unroll
        for (int nf = 0; nf < NF; ++nf) {
            const int cg = co_blk + cw0 + nf * 16 + (lhi << 2);  // first of 4 co
            float sc[4], bi[4];
#pragma unroll
            for (int r = 0; r < 4; r++) {
                int c = min(cg + r, COclamp - 1);
                sc[r] = g[c] * BNS; bi[r] = bia[c];
            }
#pragma unroll
            for (int mf = 0; mf < MF; ++mf) {
                f32x4 a = acc[nf][mf];
                u16x4 ov;
#pragma unroll
                for (int r = 0; r < 4; r++) {
                    float v = fmaf(a[r], sc[r], bi[r]);
                    if (relu) v = fmaxf(v, 0.f);
                    ov[r] = f2b(v);
                }
                int px = (int)bx * BM + wpx + mf * 16 + l15;
                unsigned off = (unsigned)(px >> 4) * (COT * 16)
                             + (unsigned)(cg >> 3) * 128
                             + (unsigned)(px & 15) * 8 + (unsigned)(cg & 7);
                *reinterpret_cast<u16x4*>(o1 + off) = ov;
            }
        }
    } else if constexpr (EPI == 1) {
        float* o1 = (float*)outp;
        const int HW = 1 << LHW;
#pragma unroll
        for (int nf = 0; nf < NF; ++nf) {
            const int cg = co_blk + cw0 + nf * 16 + (lhi << 2);
            float sc[4], bi[4];
#pragma unroll
            for (int r = 0; r < 4; r++) {
                int c = min(cg + r, COclamp - 1);
                sc[r] = g[c] * BNS; bi[r] = bia[c];
            }
#pragma unroll
            for (int mf = 0; mf < MF; ++mf) {
                int px = (int)bx * BM + wpx + mf * 16 + l15;
                int b = px >> LHW, phw = px & (HW - 1);
#pragma unroll
                for (int r = 0; r < 4; r++) {
                    float v = fmaf(acc[nf][mf][r], sc[r], bi[r]);
                    if (relu) v = fmaxf(v, 0.f);
                    o1[((size_t)(b * COT + cg + r)) * HW + phw] = v;
                }
            }
        }
    } else if constexpr (EPI == 2) {
        // fused channel-25 softmax (COT == 32, one block = row)
        __syncthreads();                     // all waves done with staging LDS
        float* sf = (float*)lds;             // [32 co][136 f32]
#pragma unroll
        for (int nf = 0; nf < NF; ++nf) {
            const int cg = cw0 + nf * 16 + (lhi << 2);
#pragma unroll
            for (int mf = 0; mf < MF; ++mf) {
                int pxl = wpx + mf * 16 + l15;
                f32x4 a = acc[nf][mf];
#pragma unroll
                for (int r = 0; r < 4; r++) {
                    int c = min(cg + r, COclamp - 1);
                    sf[(cg + r) * 136 + pxl] = fmaf(a[r], g[c] * BNS, bia[c]);
                }
            }
        }
        __syncthreads();
        if (tid < BM) {
            int gpx = (int)bx * BM + tid;
            float v[25];
#pragma unroll
            for (int c = 0; c < 25; ++c) v[c] = sf[c * 136 + tid];
            float m = v[0];
#pragma unroll
            for (int c = 1; c < 25; ++c) m = fmaxf(m, v[c]);
            float s = 0.f;
#pragma unroll
            for (int c = 0; c < 25; ++c) { v[c] = __expf(v[c] - m); s += v[c]; }
            float inv = 1.f / s;
            ushort_t* o1 = (ushort_t*)outp;
            unsigned base = (unsigned)(gpx >> 4) * (32 * 16) + (unsigned)(gpx & 15) * 8;
#pragma unroll
            for (int q = 0; q < 3; ++q) {
                u16x8 ov;
#pragma unroll
                for (int k = 0; k < 8; k++) ov[k] = f2b(v[q * 8 + k] * inv);
                *reinterpret_cast<u16x8*>(o1 + base + q * 128) = ov;
            }
            o1[base + 384] = f2b(v[24] * inv);
        }
    } else {
        // EPI == 4: fused w2 1x1 GEMM + bn2 + relu + coalesced f32 NCHW out.
        // Requires BM==128, BN==COT==128, WSX==2, NPH even (last phase=buf1).
#pragma unroll
        for (int nf = 0; nf < NF; ++nf) {
            const int cg = cw0 + nf * 16 + (lhi << 2);
            float sc[4], bi[4];
#pragma unroll
            for (int r = 0; r < 4; r++) { sc[r] = g[cg + r] * BNS; bi[r] = bia[cg + r]; }
#pragma unroll
            for (int mf = 0; mf < MF; ++mf) {
                f32x4 a = acc[nf][mf];
                u16x4 ov;
#pragma unroll
                for (int r = 0; r < 4; r++)
                    ov[r] = f2b(fmaxf(fmaf(a[r], sc[r], bi[r]), 0.f));
                int pxl = wpx + mf * 16 + l15;
                unsigned off = (unsigned)(pxl >> 4) * 4096
                             + (unsigned)(cg >> 5) * 1024
                             + (unsigned)((cg >> 3) & 3) * 256
                             + (unsigned)(pxl & 15) * 16 + (unsigned)(cg & 7) * 2;
                *reinterpret_cast<u16x4*>((char*)lds + off) = ov;
            }
        }
        __syncthreads();                 // buf1 reads done everywhere; y1 visible
        // stage w2 (32 x 1KB units, linear prepped layout) into buf1 area
#pragma unroll
        for (int i = 0; i < 8; ++i) {
            int U = i * 4 + w;
            glds16(ws0 + offW2 + (unsigned)U * 512 + (unsigned)(lane * 8),
                   lds + BUF + U * 1024);
        }
        wait_v<0, true>();
        __builtin_amdgcn_s_barrier();
        __builtin_amdgcn_sched_barrier(0);
        f32x4 acc2[NF][MF];
#pragma unroll
        for (int nf = 0; nf < NF; ++nf)
#pragma unroll
            for (int mf = 0; mf < MF; ++mf)
                acc2[nf][mf] = (f32x4){0.f, 0.f, 0.f, 0.f};
        __builtin_amdgcn_s_setprio(1);
#pragma unroll
        for (int kc = 0; kc < 4; ++kc) {
            bf16x8 af[MF], wf[NF];
#pragma unroll
            for (int mf = 0; mf < MF; ++mf) {
                int pxl = wpx + mf * 16 + l15;
                af[mf] = *reinterpret_cast<const bf16x8*>(
                    (char*)lds + (pxl >> 4) * 4096 + kc * 1024
                               + (lhi << 8) + (pxl & 15) * 16);
            }
#pragma unroll
            for (int nf = 0; nf < NF; ++nf)
                wf[nf] = *reinterpret_cast<const bf16x8*>(
                    (char*)lds + BUF + kc * 8192 + wA[nf]);
#pragma unroll
            for (int nf = 0; nf < NF; ++nf)
#pragma unroll
                for (int mf = 0; mf < MF; ++mf)
                    acc2[nf][mf] = __builtin_amdgcn_mfma_f32_16x16x32_bf16(
                        wf[nf], af[mf], acc2[nf][mf], 0, 0, 0);
        }
        __builtin_amdgcn_s_setprio(0);
        __syncthreads();                 // LDS free for the f32 exchange
        float* o1 = (float*)outp;
        float* sf = (float*)lds;         // [64 co][132 f32] per half
        const int phw_base = (int)((bx & 127u) * 128);
        const int bimg = (int)(bx >> 7);
        const int lane32 = tid & 31, cog = tid >> 5;
#pragma unroll
        for (int c = 0; c < 2; ++c) {
            if (c) __syncthreads();
            if (cw0 == c * 64) {
#pragma unroll
                for (int nf = 0; nf < NF; ++nf) {
                    const int cgl = nf * 16 + (lhi << 2);
                    const int cg  = c * 64 + cgl;
                    float sc[4], bi[4];
#pragma unroll
                    for (int r = 0; r < 4; r++) { sc[r] = g2[cg + r] * BNS; bi[r] = bia2[cg + r]; }
#pragma unroll
                    for (int mf = 0; mf < MF; ++mf) {
                        int pxl = wpx + mf * 16 + l15;
                        f32x4 a = acc2[nf][mf];
#pragma unroll
                        for (int r = 0; r < 4; r++)
                            sf[(cgl + r) * 132 + pxl] =
                                fmaxf(fmaf(a[r], sc[r], bi[r]), 0.f);
                    }
                }
            }
            __syncthreads();
#pragma unroll
            for (int j = 0; j < 8; ++j) {
                int col = cog + j * 8;           // 0..63
                f32x4 v = *reinterpret_cast<const f32x4*>(sf + col * 132 + lane32 * 4);
                *reinterpret_cast<f32x4*>(
                    o1 + (((size_t)bimg * 128 + c * 64 + col) << 14)
                       + phw_base + lane32 * 4) = v;
            }
        }
    }
}

// ============================================================================
// 2x bilinear resize (align-corners linspace), T16 bf16, C=64, 64x64 -> 128x128
// ============================================================================
__global__ __launch_bounds__(256)
void resize2x_t16(const ushort_t* __restrict__ in, ushort_t* __restrict__ out)
{
    int t = blockIdx.x * 256 + threadIdx.x;
    int cg = t & 7;
    int opx = t >> 3;
    int xo = opx & 127;
    int rest = opx >> 7;
    int yo = rest & 127;
    int b  = rest >> 7;
    float fy = (float)yo * 63.f / 127.f;
    float fx = (float)xo * 63.f / 127.f;
    int y0 = (int)fy, x0 = (int)fx;
    float wy = fy - (float)y0, wx = fx - (float)x0;
    int y1 = min(y0 + 1, 63), x1 = min(x0 + 1, 63);
    int qb = b * 4096;
#define RD(Y, X) (*reinterpret_cast<const bf16x8*>(in + \
    (unsigned)(((qb + (Y) * 64 + (X)) >> 4) * 1024) + cg * 128 + ((qb + (Y) * 64 + (X)) & 15) * 8))
    bf16x8 v00 = RD(y0, x0), v01 = RD(y0, x1), v10 = RD(y1, x0), v11 = RD(y1, x1);
#undef RD
    u16x8 o;
#pragma unroll
    for (int k = 0; k < 8; k++) {
        float l = b2f((ushort_t)v00[k]) * (1.f - wy) + b2f((ushort_t)v10[k]) * wy;
        float r = b2f((ushort_t)v01[k]) * (1.f - wy) + b2f((ushort_t)v11[k]) * wy;
        o[k] = f2b(l * (1.f - wx) + r * wx);
    }
    *reinterpret_cast<u16x8*>(out + (unsigned)(opx >> 4) * 1024 + cg * 128 + (opx & 15) * 8) = o;
}

// ============================================================================
// CARAFE combine (T16 bf16, C=64, H=W=128)
// ============================================================================
__global__ __launch_bounds__(256)
void carafe25(const ushort_t* __restrict__ wm, const ushort_t* __restrict__ xu,
              ushort_t* __restrict__ out)
{
    int t = blockIdx.x * 256 + threadIdx.x;
    int cg = t & 7;
    int px = t >> 3;
    int x = px & 127;
    int y = (px >> 7) & 127;
    const ushort_t* wp = wm + (unsigned)(px >> 4) * 512 + (px & 15) * 8;
    u16x8 r0 = *reinterpret_cast<const u16x8*>(wp);
    u16x8 r1 = *reinterpret_cast<const u16x8*>(wp + 128);
    u16x8 r2 = *reinterpret_cast<const u16x8*>(wp + 256);
    float v[25];
#pragma unroll
    for (int k = 0; k < 8; k++) v[k]      = b2f(r0[k]);
#pragma unroll
    for (int k = 0; k < 8; k++) v[8 + k]  = b2f(r1[k]);
#pragma unroll
    for (int k = 0; k < 8; k++) v[16 + k] = b2f(r2[k]);
    v[24] = b2f(wp[384]);

    float acc[8];
#pragma unroll
    for (int k = 0; k < 8; k++) acc[k] = 0.f;
#pragma unroll
    for (int i = 0; i < 5; i++) {
        int yy = y + 2 * i - 4;
#pragma unroll
        for (int j = 0; j < 5; j++) {
            int xx = x + 2 * j - 4;
            if (yy >= 0 && yy < 128 && xx >= 0 && xx < 128) {
                int q = px + (2 * i - 4) * 128 + (2 * j - 4);
                bf16x8 xv = *reinterpret_cast<const bf16x8*>(
                    xu + (unsigned)(q >> 4) * 1024 + cg * 128 + (q & 15) * 8);
                float wv = v[i * 5 + j];
#pragma unroll
                for (int k = 0; k < 8; k++)
                    acc[k] = fmaf(wv, b2f((ushort_t)xv[k]), acc[k]);
            }
        }
    }
    u16x8 o;
#pragma unroll
    for (int k = 0; k < 8; k++) o[k] = f2b(acc[k]);
    *reinterpret_cast<u16x8*>(out + (unsigned)(px >> 4) * 1024 + cg * 128 + (px & 15) * 8) = o;
}

// ============================================================================
extern "C" void kernel_launch(void* const* d_in, const int* in_sizes, int n_in,
                              void* d_out, int out_size, void* d_ws, size_t ws_size,
                              hipStream_t stream)
{
    const float* x_h      = (const float*)d_in[0];
    const float* x_l      = (const float*)d_in[1];
    const float* w_reduce = (const float*)d_in[2];
    const float* g_reduce = (const float*)d_in[3];
    const float* b_reduce = (const float*)d_in[4];
    const float* w1       = (const float*)d_in[5];
    const float* g1       = (const float*)d_in[6];
    const float* b1       = (const float*)d_in[7];
    const float* w2       = (const float*)d_in[8];
    const float* g2       = (const float*)d_in[9];
    const float* b2       = (const float*)d_in[10];
    const float* w_enc    = (const float*)d_in[11];
    const float* g_enc    = (const float*)d_in[12];
    const float* b_enc    = (const float*)d_in[13];
    const float* w_out1   = (const float*)d_in[14];
    const float* g_out1   = (const float*)d_in[15];
    const float* b_out1   = (const float*)d_in[16];
    const float* w_out2   = (const float*)d_in[17];
    const float* g_out2   = (const float*)d_in[18];
    const float* b_out2   = (const float*)d_in[19];

    ushort_t* ws0 = (ushort_t*)d_ws;

    const unsigned oXHC = OFF_R1;   // (16384, 256) T16
    const unsigned oC1  = OFF_R2;   // (16384, 64)
    const unsigned oXR  = OFF_R3;   // (16384, 64)
    const unsigned oX1  = OFF_R4;   // (65536, 64)
    const unsigned oXLC = OFF_R5;   // (65536, 128)
    const unsigned oX2  = OFF_R1;   // (65536, 64)   xh_c dead
    const unsigned oWM  = OFF_R6;   // (65536, 32)
    const unsigned oXU  = OFF_R4;   // (65536, 64)   x1 dead AFTER enc conv
    const unsigned oXB  = OFF_R1;   // (65536, 64)   x2 dead

    // 0) weights + zero page + both activation conversions, ONE dispatch
    prep_all<<<2192, 256, 0, stream>>>(w_reduce, w1, w2, w_enc, w_out1, w_out2,
                                       x_h, x_l, ws0);
    // 1) DUAL: xr = cbr3x3(xh_c, w_reduce) AND c1 = cbr1x1(xh_c, w1), 2 blk/CU
    conv_dual<<<dim3(256, 2), 256, 0, stream>>>(
        ws0, oXHC, E_BWR, E_BW1, g_reduce, b_reduce, g1, b1,
        ws0 + oXR, ws0 + oC1);
    // 2) x1 = resize2x(c1)
    resize2x_t16<<<2048, 256, 0, stream>>>(ws0 + oC1, ws0 + oX1);
    // 3) x2 = cbr1x1(xl_c, w2): M=65536 K=128 CO=64, G=1 DEP=3
    conv_lds<1, 128, 128, 0, 64, 64, 1, 2, 3, 0><<<dim3(512, 1), 256, 0, stream>>>(
        ws0, oXLC, 0u, E_BW2, g2, b2, 64, ws0 + oX2, 128, 14, 1,
        0u, nullptr, nullptr);
    // 4) wm = conv3x3(concat(x1,x2), w_enc) + fused softmax-25, WSX=4 DEP=3
    conv_lds<9, 128, 64, 64, 32, 32, 1, 4, 3, 2><<<dim3(512, 1), 256, 0, stream>>>(
        ws0, oX1, oX2, E_BWE, g_enc, b_enc, 25, ws0 + oWM, 128, 14, 0,
        0u, nullptr, nullptr);
    // 5) xu = resize2x(xr)   (x1 dead now -> R4 reuse is safe)
    resize2x_t16<<<2048, 256, 0, stream>>>(ws0 + oXR, ws0 + oXU);
    // 6) X = carafe(wm, xu)
    carafe25<<<2048, 256, 0, stream>>>(ws0 + oWM, ws0 + oXU, ws0 + oXB);
    // 7) FUSED: y1 = cbr3x3(concat(X, xl_c), w_out1) -> (in-LDS) ->
    //           out = cbr1x1(y1, w_out2) -> d_out f32 (coalesced)
    conv_lds<9, 128, 64, 128, 128, 128, 1, 2, 2, 4><<<dim3(512, 1), 256, 0, stream>>>(
        ws0, oXB, oXLC, E_BWO1, g_out1, b_out1, 128, d_out, 128, 14, 1,
        E_BWO2, g_out2, b_out2);
}